// Round 1
// baseline (224.967 us; speedup 1.0000x reference)
//
#include <hip/hip_runtime.h>

// Problem constants (from reference):
//   x: [B=32, C=1, F=257, T=4096] float32 log-magnitude spectrogram
//   SHIFT_BINS = 20.0 / (16000/512) = 0.64  -> f_low = f, f_high = f+1
//   out[b,f,t] = log10((1-a)*10^x[b,f,t] + a*10^x[b,f+1,t] + 1e-8), f < 256
//   out[b,256,t] = log10(1e-8)   (valid mask false at the top bin)
#define B_DIM 32
#define F_DIM 257
#define T_DIM 4096
#define EPS_F 1e-8f

// log2(10) and log10(2) in fp32-exact-enough form
#define LOG2_10  3.32192809488736234787f
#define LOG10_2  0.30102999566398119521f

__device__ __forceinline__ float pow10_fast(float v) {
    // 10^v = 2^(v * log2(10)); v_exp_f32 is ~1 ulp — far under the 0.16 absmax threshold
    return __builtin_amdgcn_exp2f(v * LOG2_10);
}

__device__ __forceinline__ float log10_fast(float v) {
    return __builtin_amdgcn_logf(v) * LOG10_2;  // v_log_f32 is log2
}

__global__ __launch_bounds__(256) void freq_shift_kernel(
        const float* __restrict__ x, float* __restrict__ out) {
    const int bf = blockIdx.x;            // flattened (b*F + f); rows are contiguous
    const int f  = bf % F_DIM;
    const long long base = (long long)bf * T_DIM;
    const int tid = threadIdx.x;

    float4* __restrict__ orow = (float4*)(out + base);

    if (f == F_DIM - 1) {
        // invalid top bin: log10(0 + 1e-8); block-uniform branch, no divergence
        const float cv = log10_fast(EPS_F);
        const float4 v = make_float4(cv, cv, cv, cv);
#pragma unroll
        for (int i = 0; i < T_DIM / 4 / 256; ++i)
            orow[i * 256 + tid] = v;
        return;
    }

    const float4* __restrict__ row0 = (const float4*)(x + base);
    const float4* __restrict__ row1 = (const float4*)(x + base + T_DIM);

    // Reproduce reference fp32 alpha: target = fl(f + 0.64f); alpha = target - f
    // (exact subtraction by Sterbenz; matches jnp float32 weak-typed arithmetic)
    const float ff     = (float)f;
    const float target = ff + 0.64f;
    const float alpha  = target - ff;
    const float beta   = 1.0f - alpha;

#pragma unroll
    for (int i = 0; i < T_DIM / 4 / 256; ++i) {
        const int j = i * 256 + tid;
        const float4 a = row0[j];
        const float4 b = row1[j];
        float4 r;
        r.x = log10_fast(beta * pow10_fast(a.x) + alpha * pow10_fast(b.x) + EPS_F);
        r.y = log10_fast(beta * pow10_fast(a.y) + alpha * pow10_fast(b.y) + EPS_F);
        r.z = log10_fast(beta * pow10_fast(a.z) + alpha * pow10_fast(b.z) + EPS_F);
        r.w = log10_fast(beta * pow10_fast(a.w) + alpha * pow10_fast(b.w) + EPS_F);
        orow[j] = r;
    }
}

extern "C" void kernel_launch(void* const* d_in, const int* in_sizes, int n_in,
                              void* d_out, int out_size, void* d_ws, size_t ws_size,
                              hipStream_t stream) {
    const float* x = (const float*)d_in[0];
    float* out = (float*)d_out;
    // grid: one block per (b,f) row; 32*257 = 8224 blocks, 256 threads,
    // 4 float4 iterations per thread covering T=4096
    dim3 grid(B_DIM * F_DIM);
    dim3 block(256);
    freq_shift_kernel<<<grid, block, 0, stream>>>(x, out);
}